// Round 1
// baseline (2783.761 us; speedup 1.0000x reference)
//
#include <hip/hip_runtime.h>

// Problem constants (fixed by reference)
#define K3c    27
#define Mc     100000
#define NINc   200000
#define NOUTc  400000
#define Cc     128
#define EPSc   1e-5f

#define NBUCK  6250          // global 64-row output buckets (NOUTc/64)
#define NCNT   (NBUCK * K3c) // 168,750 keys: key = bucket*27 + k
#define BPK    391           // map-pass blocks per k (391*256 >= 100000)

// ws layout (byte offsets)
#define WS_STATS   0u          // 512 floats: sum | ssq | scale | shift
#define WS_COUNTS  4096u       // NCNT u32
#define WS_SPK     1048576u    // 2.7M u32 packed sorted pairs (im|k|omlow)
#define WS_WFH     25165824u   // 27*2048 lanes * 8 shorts  (884,736 B)
#define WS_WFL     26214400u   // same

typedef __attribute__((ext_vector_type(8))) short short8;
typedef __attribute__((ext_vector_type(4))) float f32x4;

__device__ inline unsigned fbits(float f) { return __builtin_bit_cast(unsigned, f); }
__device__ inline float bfloat(unsigned u) { return __builtin_bit_cast(float, u); }

__device__ inline unsigned short bf16_rne(float f) {
    unsigned u = fbits(f);
    u += 0x7FFFu + ((u >> 16) & 1u);
    return (unsigned short)(u >> 16);
}

// split f into truncated-bf16 hi and truncated-bf16 of the residual
#define SPLIT1(F, H, L) { unsigned hb_ = fbits(F) & 0xFFFF0000u; \
                          (H) = (short)(hb_ >> 16); \
                          (L) = (short)(fbits((F) - bfloat(hb_)) >> 16); }

// ---------------------------------------------------------------------------
// Kernel 1: zero counters + stats (output no longer needs zeroing!)
// ---------------------------------------------------------------------------
__global__ __launch_bounds__(256) void zero2_kernel(float* __restrict__ stats,
                                                    unsigned* __restrict__ counts) {
    int idx = blockIdx.x * 256 + threadIdx.x;
    if (idx < NCNT) counts[idx] = 0u;
    if (idx < 512) stats[idx] = 0.f;
}

// ---------------------------------------------------------------------------
// Kernel 2: W -> per-lane MFMA B-fragment layout, RNE hi/lo bf16 split
// (unchanged from verified version)
// ---------------------------------------------------------------------------
__global__ __launch_bounds__(256) void wprep_kernel(const float* __restrict__ W,
                                                    short8* __restrict__ wfh,
                                                    short8* __restrict__ wfl) {
    int tid = blockIdx.x * 256 + threadIdx.x;     // grid = 216 blocks exactly
    int k     = tid >> 11;
    int rem   = tid & 2047;
    int kstep = rem >> 9;
    int cb    = (rem >> 6) & 7;
    int lane  = rem & 63;
    int n   = cb * 16 + (lane & 15);
    int kk0 = kstep * 32 + (lane >> 4) * 8;
    const float* src = W + k * (Cc * Cc) + kk0 * Cc + n;
    short8 h, l;
#pragma unroll
    for (int j = 0; j < 8; ++j) {
        float f = src[j * Cc];
        unsigned short hb = bf16_rne(f);
        h[j] = (short)hb;
        float hf = bfloat(((unsigned)hb) << 16);
        l[j] = (short)bf16_rne(f - hf);
    }
    wfh[tid] = h;
    wfl[tid] = l;
}

// ---------------------------------------------------------------------------
// Kernel 3: histogram of pairs by global key (bucket-major, k-minor)
// ---------------------------------------------------------------------------
__global__ __launch_bounds__(256) void hist2_kernel(const int* __restrict__ out_maps,
                                                    unsigned* __restrict__ counts) {
    int b = blockIdx.x;
    int k = b / BPK;
    int m = (b - k * BPK) * 256 + threadIdx.x;
    if (m < Mc) {
        int om = out_maps[k * Mc + m];
        atomicAdd(&counts[(unsigned)(om >> 6) * 27u + (unsigned)k], 1u);
    }
}

// ---------------------------------------------------------------------------
// Kernel 4: single-block exclusive scan over all 168,750 counters (in place).
// (unchanged)
// ---------------------------------------------------------------------------
__global__ __launch_bounds__(1024) void scan_kernel(unsigned* __restrict__ counts) {
    __shared__ unsigned lds[1024];
    const int t = threadIdx.x;
    const int CHUNK = 165;                         // 1024*165 >= NCNT
    int base = t * CHUNK;
    unsigned s = 0;
    for (int j = 0; j < CHUNK; ++j) {
        int i = base + j;
        if (i < NCNT) s += counts[i];
    }
    lds[t] = s;
    __syncthreads();
    for (int off = 1; off < 1024; off <<= 1) {
        unsigned v = (t >= off) ? lds[t - off] : 0u;
        __syncthreads();
        lds[t] += v;
        __syncthreads();
    }
    unsigned run = lds[t] - s;                     // exclusive carry
    for (int j = 0; j < CHUNK; ++j) {
        int i = base + j;
        if (i < NCNT) {
            unsigned c = counts[i];
            counts[i] = run;
            run += c;
        }
    }
}

// ---------------------------------------------------------------------------
// Kernel 5: scatter packed pairs into globally-sorted order.
// After this, counts[key] = END offset of that key's range.
// Packed pair: im (bits 0-17) | k (18-22) | om&63 (23-28)
// ---------------------------------------------------------------------------
__global__ __launch_bounds__(256) void build2_kernel(const int* __restrict__ in_maps,
                                                     const int* __restrict__ out_maps,
                                                     unsigned* __restrict__ offs,
                                                     unsigned* __restrict__ sorted_pk) {
    int b = blockIdx.x;
    int k = b / BPK;
    int m = (b - k * BPK) * 256 + threadIdx.x;
    if (m < Mc) {
        int om = out_maps[k * Mc + m];
        int im = in_maps[k * Mc + m];
        unsigned pos = atomicAdd(&offs[(unsigned)(om >> 6) * 27u + (unsigned)k], 1u);
        sorted_pk[pos] = (unsigned)im | ((unsigned)k << 18) | ((unsigned)(om & 63) << 23);
    }
}

// ---------------------------------------------------------------------------
// Kernel 6: output-major GEMM. One block = one 64-row output tile.
// LDS fp32 accumulator [64][128]; per-k pair groups, 32 pairs per B load
// (two 16-row MFMA subtiles share the B fragments). Scatter via ds_add_f32.
// Tile written ONCE (no global atomics, no zero-init); per-channel
// sum/ssq fused into the epilogue.
// ---------------------------------------------------------------------------
__global__ __launch_bounds__(256, 4) void gemm2_kernel(
    const float* __restrict__ feats,
    const short8* __restrict__ wfh, const short8* __restrict__ wfl,
    const unsigned* __restrict__ counts,      // end offsets per key
    const unsigned* __restrict__ sorted_pk,
    float* __restrict__ out, float* __restrict__ stats)
{
    __shared__ float accs[64 * Cc];           // 32 KB fp32 accumulator tile
    __shared__ unsigned earr[28];             // earr[0]=tile start, earr[k+1]=end of k-group
    __shared__ int kctr;
    __shared__ float sred[Cc], qred[Cc];

    const int b = blockIdx.x;
    const int t = threadIdx.x;

    if (t < 27) earr[t + 1] = counts[b * 27 + t];
    if (t == 27) earr[0] = (b == 0) ? 0u : counts[b * 27 - 1];
    if (t == 28) kctr = 0;
    {
        f32x4* a4 = (f32x4*)accs;
        const f32x4 z = {0.f, 0.f, 0.f, 0.f};
#pragma unroll
        for (int i = 0; i < 8; ++i) a4[t + i * 256] = z;
    }
    __syncthreads();

    const int lane = t & 63;
    const int m    = lane & 15;
    const int quad = lane >> 4;

    for (;;) {
        int kk = 0;
        if (lane == 0) kk = atomicAdd(&kctr, 1);
        kk = __shfl(kk, 0);
        if (kk >= K3c) break;
        const unsigned sk = earr[kk];
        const unsigned ek = earr[kk + 1];
        for (unsigned p0 = sk; p0 < ek; p0 += 32) {
            const int nA = (int)(ek - p0);
            const int n0 = nA < 16 ? nA : 16;
            int n1 = nA - 16; n1 = n1 < 0 ? 0 : (n1 > 16 ? 16 : n1);
            const bool two = (n1 > 0);

            unsigned pk0 = (m < n0) ? sorted_pk[p0 + m] : 0u;
            unsigned pk1 = (two && m < n1) ? sorted_pk[p0 + 16 + m] : 0u;
            const float* ap0 = feats + (long)(pk0 & 0x3FFFFu) * Cc + quad * 8;
            const float* ap1 = feats + (long)(pk1 & 0x3FFFFu) * Cc + quad * 8;

            f32x4 acc0[8], acc1[8];
            const f32x4 z = {0.f, 0.f, 0.f, 0.f};
#pragma unroll
            for (int cb = 0; cb < 8; ++cb) { acc0[cb] = z; acc1[cb] = z; }

            for (int kstep = 0; kstep < 4; ++kstep) {
                short8 a0h, a0l, a1h, a1l;
                {
                    float4 v0 = *(const float4*)(ap0 + kstep * 32);
                    float4 v1 = *(const float4*)(ap0 + kstep * 32 + 4);
                    SPLIT1(v0.x, a0h[0], a0l[0]); SPLIT1(v0.y, a0h[1], a0l[1]);
                    SPLIT1(v0.z, a0h[2], a0l[2]); SPLIT1(v0.w, a0h[3], a0l[3]);
                    SPLIT1(v1.x, a0h[4], a0l[4]); SPLIT1(v1.y, a0h[5], a0l[5]);
                    SPLIT1(v1.z, a0h[6], a0l[6]); SPLIT1(v1.w, a0h[7], a0l[7]);
                }
                if (two) {
                    float4 v0 = *(const float4*)(ap1 + kstep * 32);
                    float4 v1 = *(const float4*)(ap1 + kstep * 32 + 4);
                    SPLIT1(v0.x, a1h[0], a1l[0]); SPLIT1(v0.y, a1h[1], a1l[1]);
                    SPLIT1(v0.z, a1h[2], a1l[2]); SPLIT1(v0.w, a1h[3], a1l[3]);
                    SPLIT1(v1.x, a1h[4], a1l[4]); SPLIT1(v1.y, a1h[5], a1l[5]);
                    SPLIT1(v1.z, a1h[6], a1l[6]); SPLIT1(v1.w, a1h[7], a1l[7]);
                }
                const int fb = ((kk * 4 + kstep) * 8) * 64 + lane;
#pragma unroll
                for (int cb = 0; cb < 8; ++cb) {
                    short8 bh = wfh[fb + cb * 64];
                    short8 bl = wfl[fb + cb * 64];
                    acc0[cb] = __builtin_amdgcn_mfma_f32_16x16x32_bf16(a0h, bh, acc0[cb], 0, 0, 0);
                    acc0[cb] = __builtin_amdgcn_mfma_f32_16x16x32_bf16(a0l, bh, acc0[cb], 0, 0, 0);
                    acc0[cb] = __builtin_amdgcn_mfma_f32_16x16x32_bf16(a0h, bl, acc0[cb], 0, 0, 0);
                    if (two) {
                        acc1[cb] = __builtin_amdgcn_mfma_f32_16x16x32_bf16(a1h, bh, acc1[cb], 0, 0, 0);
                        acc1[cb] = __builtin_amdgcn_mfma_f32_16x16x32_bf16(a1l, bh, acc1[cb], 0, 0, 0);
                        acc1[cb] = __builtin_amdgcn_mfma_f32_16x16x32_bf16(a1h, bl, acc1[cb], 0, 0, 0);
                    }
                }
            }

            // scatter into LDS tile: C/D layout col = cb*16 + m, pair-row = quad*4 + reg
#pragma unroll
            for (int reg = 0; reg < 4; ++reg) {
                const int prow = quad * 4 + reg;
                unsigned pks = (unsigned)__shfl((int)pk0, prow);
                if (prow < n0) {
                    float* dst = accs + ((pks >> 23) & 63u) * Cc + m;
#pragma unroll
                    for (int cb = 0; cb < 8; ++cb)
                        __hip_atomic_fetch_add(dst + cb * 16, acc0[cb][reg],
                                               __ATOMIC_RELAXED, __HIP_MEMORY_SCOPE_WORKGROUP);
                }
            }
            if (two) {
#pragma unroll
                for (int reg = 0; reg < 4; ++reg) {
                    const int prow = quad * 4 + reg;
                    unsigned pks = (unsigned)__shfl((int)pk1, prow);
                    if (prow < n1) {
                        float* dst = accs + ((pks >> 23) & 63u) * Cc + m;
#pragma unroll
                        for (int cb = 0; cb < 8; ++cb)
                            __hip_atomic_fetch_add(dst + cb * 16, acc1[cb][reg],
                                                   __ATOMIC_RELAXED, __HIP_MEMORY_SCOPE_WORKGROUP);
                    }
                }
            }
        }
    }
    __syncthreads();

    // --- write tile once, coalesced float4 ---
    {
        const int c4 = t & 31;
        const int rg = t >> 5;
        float4* dst4 = (float4*)(out + (long)b * 64 * Cc);
        const float4* a4 = (const float4*)accs;
#pragma unroll
        for (int i = 0; i < 8; ++i) {
            const int r = rg * 8 + i;
            dst4[r * 32 + c4] = a4[r * 32 + c4];
        }
    }
    // --- fused per-channel partial stats ---
    {
        const int col  = t & 127;
        const int half = t >> 7;
        float s = 0.f, q = 0.f;
        for (int r = half * 32; r < half * 32 + 32; ++r) {
            float v = accs[r * Cc + col];
            s += v; q += v * v;
        }
        if (half) { sred[col] = s; qred[col] = q; }
        __syncthreads();
        if (!half) {
            s += sred[col]; q += qred[col];
            unsafeAtomicAdd(&stats[col], s);
            unsafeAtomicAdd(&stats[Cc + col], q);
        }
    }
}

// ---------------------------------------------------------------------------
// Kernel 7: finalize BN scale/shift per channel (unchanged)
// ---------------------------------------------------------------------------
__global__ void finalize_kernel(const float* __restrict__ gamma,
                                const float* __restrict__ beta,
                                float* __restrict__ stats) {
    int c = threadIdx.x;
    float inv_n = 1.0f / (float)NOUTc;
    float mean = stats[c] * inv_n;
    float var  = stats[Cc + c] * inv_n - mean * mean;
    float scale = gamma[c] * rsqrtf(var + EPSc);
    stats[2 * Cc + c] = scale;
    stats[3 * Cc + c] = beta[c] - mean * scale;
}

// ---------------------------------------------------------------------------
// Kernel 8: in-place normalize  y = out*scale[c] + shift[c] (unchanged)
// ---------------------------------------------------------------------------
__global__ __launch_bounds__(256) void norm_kernel(float4* __restrict__ out4,
                                                   const float* __restrict__ stats) {
    const float4* stats4 = (const float4*)stats;
    int idx0 = blockIdx.x * blockDim.x + threadIdx.x;
    int c4 = idx0 & 31;
    float4 sc = stats4[64 + c4];
    float4 sh = stats4[96 + c4];
    const int n4 = NOUTc * (Cc / 4);
    const int stride = gridDim.x * blockDim.x;
    for (int i = idx0; i < n4; i += stride) {
        float4 v = out4[i];
        v.x = v.x * sc.x + sh.x;
        v.y = v.y * sc.y + sh.y;
        v.z = v.z * sc.z + sh.z;
        v.w = v.w * sc.w + sh.w;
        out4[i] = v;
    }
}

// ---------------------------------------------------------------------------
extern "C" void kernel_launch(void* const* d_in, const int* in_sizes, int n_in,
                              void* d_out, int out_size, void* d_ws, size_t ws_size,
                              hipStream_t stream) {
    const float* feats    = (const float*)d_in[0];
    const float* W        = (const float*)d_in[1];
    const float* gamma    = (const float*)d_in[2];
    const float* beta     = (const float*)d_in[3];
    const int*   in_maps  = (const int*)d_in[4];
    const int*   out_maps = (const int*)d_in[5];
    float* out = (float*)d_out;

    char* ws = (char*)d_ws;
    float*    stats     = (float*)(ws + WS_STATS);
    unsigned* counts    = (unsigned*)(ws + WS_COUNTS);
    unsigned* sorted_pk = (unsigned*)(ws + WS_SPK);
    short8*   wfh       = (short8*)(ws + WS_WFH);
    short8*   wfl       = (short8*)(ws + WS_WFL);

    zero2_kernel<<<660, 256, 0, stream>>>(stats, counts);
    wprep_kernel<<<216, 256, 0, stream>>>(W, wfh, wfl);
    hist2_kernel<<<K3c * BPK, 256, 0, stream>>>(out_maps, counts);
    scan_kernel<<<1, 1024, 0, stream>>>(counts);
    build2_kernel<<<K3c * BPK, 256, 0, stream>>>(in_maps, out_maps, counts, sorted_pk);
    gemm2_kernel<<<NBUCK, 256, 0, stream>>>(feats, wfh, wfl, counts, sorted_pk, out, stats);
    finalize_kernel<<<1, 128, 0, stream>>>(gamma, beta, stats);
    norm_kernel<<<4096, 256, 0, stream>>>((float4*)out, stats);
}